// Round 2
// baseline (429.606 us; speedup 1.0000x reference)
//
#include <hip/hip_runtime.h>
#include <hip/hip_bf16.h>

#define DEVI __device__ __forceinline__

typedef __attribute__((ext_vector_type(8))) short bfrag8;  // 8 bf16 (4 VGPRs)
typedef __attribute__((ext_vector_type(4))) float f32x4;

constexpr int NROW = 8192;
constexpr int DDIM = 768;
constexpr int BM = 128, BN = 128, BK = 64;
constexpr int KSTEPS = DDIM / BK;          // 12
constexpr int TILE_BYTES = BM * BK * 2;    // 16384
constexpr int NTI = NROW / BM;             // 64 row tiles
constexpr int NTJ = NROW / BN;             // 64 col tiles

// ---- exact monotonic float<->uint key for atomicMax on floats ----
DEVI unsigned fkey(float f) {
  unsigned b = __float_as_uint(f);
  return (b & 0x80000000u) ? ~b : (b | 0x80000000u);
}
DEVI float funkey(unsigned k) {
  unsigned b = (k & 0x80000000u) ? (k ^ 0x80000000u) : ~k;
  return __uint_as_float(b);
}

// ---------------------------------------------------------------------------
// K1: fp32 -> (hi,lo) bf16 split + row norms + rowmax init
// ---------------------------------------------------------------------------
__global__ __launch_bounds__(256) void prep_kernel(
    const float* __restrict__ ex, const float* __restrict__ ey,
    __hip_bfloat16* __restrict__ xhi, __hip_bfloat16* __restrict__ xlo,
    __hip_bfloat16* __restrict__ yhi, __hip_bfloat16* __restrict__ ylo,
    float* __restrict__ nx, float* __restrict__ ny,
    unsigned* __restrict__ rowmax)
{
  const int row = blockIdx.x;
  const int which = blockIdx.y;
  const float* __restrict__ src = which ? ey : ex;
  __hip_bfloat16* __restrict__ hi = which ? yhi : xhi;
  __hip_bfloat16* __restrict__ lo = which ? ylo : xlo;
  float* __restrict__ nrm = which ? ny : nx;

  const int tid = threadIdx.x;
  float ss = 0.f;
  for (int c = tid; c < DDIM; c += 256) {
    float x = src[(size_t)row * DDIM + c];
    ss += x * x;
    __hip_bfloat16 h = __float2bfloat16(x);
    float hf = __bfloat162float(h);
    __hip_bfloat16 l = __float2bfloat16(x - hf);
    hi[(size_t)row * DDIM + c] = h;
    lo[(size_t)row * DDIM + c] = l;
  }
#pragma unroll
  for (int off = 32; off > 0; off >>= 1) ss += __shfl_xor(ss, off, 64);
  __shared__ float red[4];
  const int wave = tid >> 6, lane = tid & 63;
  if (lane == 0) red[wave] = ss;
  __syncthreads();
  if (tid == 0) {
    nrm[row] = sqrtf(red[0] + red[1] + red[2] + red[3]);
    if (!which) rowmax[row] = 0u;  // below every real cosine key
  }
}

// ---------------------------------------------------------------------------
// K2: split-bf16 GEMM (3 MFMA passes ~ fp32 accuracy) + fused scale + row-max
// ---------------------------------------------------------------------------

// Stage one 128x64-bf16 tile (row-major, 128B rows) global->LDS.
// LDS dest is linear (global_load_lds constraint); the XOR bank-swizzle
// (chunk ^= row&7 on 16B chunks) is realized by pre-swizzling the per-lane
// GLOBAL source address (guide m173 pattern).
DEVI void stage(const char* __restrict__ src, int row0, int k0, char* ldst,
                int wave, int lane)
{
#pragma unroll
  for (int c = 0; c < 4; ++c) {
    int r = wave * 32 + c * 8 + (lane >> 3);       // row in tile
    int jlog = (lane & 7) ^ (r & 7);               // logical 16B chunk to fetch
    const char* g = src + (size_t)(row0 + r) * (DDIM * 2)
                        + (size_t)(k0 * 2) + jlog * 16;
    char* l = ldst + (wave * 32 + c * 8) * 128;    // wave-uniform base
    __builtin_amdgcn_global_load_lds(
        (const __attribute__((address_space(1))) void*)g,
        (__attribute__((address_space(3))) void*)l, 16, 0, 0);
  }
}

// Read one 16B MFMA fragment from the swizzled tile.
DEVI bfrag8 ld_frag(const char* base, int r, int kchunk) {
  int phys = kchunk ^ (r & 7);
  return *reinterpret_cast<const bfrag8*>(base + r * 128 + phys * 16);
}

__global__ __launch_bounds__(256, 2) void gemm_max_kernel(
    const __hip_bfloat16* __restrict__ xhi, const __hip_bfloat16* __restrict__ xlo,
    const __hip_bfloat16* __restrict__ yhi, const __hip_bfloat16* __restrict__ ylo,
    const float* __restrict__ nx, const float* __restrict__ ny,
    unsigned* __restrict__ rowmax)
{
  __shared__ __align__(16) char lds[4 * TILE_BYTES];  // 64 KB
  char* ldsXh = lds;
  char* ldsXl = lds + TILE_BYTES;
  char* ldsYh = lds + 2 * TILE_BYTES;
  char* ldsYl = lds + 3 * TILE_BYTES;

  const int tid = threadIdx.x;
  const int lane = tid & 63;
  const int wave = tid >> 6;
  const int wr = wave >> 1, wc = wave & 1;   // 2x2 waves over 128x128 tile

  // XCD-aware swizzle (4096 % 8 == 0 -> simple form is bijective)
  const int bid = blockIdx.x;
  const int swz = (bid & 7) * ((NTI * NTJ) / 8) + (bid >> 3);
  const int bi = swz >> 6;   // row tile
  const int bj = swz & 63;   // col tile

  f32x4 acc[4][4];
#pragma unroll
  for (int m = 0; m < 4; ++m)
#pragma unroll
    for (int n = 0; n < 4; ++n) acc[m][n] = f32x4{0.f, 0.f, 0.f, 0.f};

  const char* gxh = (const char*)xhi;
  const char* gxl = (const char*)xlo;
  const char* gyh = (const char*)yhi;
  const char* gyl = (const char*)ylo;

  for (int ks = 0; ks < KSTEPS; ++ks) {
    const int k0 = ks * BK;
    __syncthreads();  // prior reads of LDS done before overwrite
    stage(gxh, bi * BM, k0, ldsXh, wave, lane);
    stage(gxl, bi * BM, k0, ldsXl, wave, lane);
    stage(gyh, bj * BN, k0, ldsYh, wave, lane);
    stage(gyl, bj * BN, k0, ldsYl, wave, lane);
    __syncthreads();  // staging complete (vmcnt drained by barrier)

#pragma unroll
    for (int kk = 0; kk < 2; ++kk) {
      bfrag8 ah[4], al[4], bh[4], bl[4];
      const int kchunk = kk * 4 + (lane >> 4);
#pragma unroll
      for (int m = 0; m < 4; ++m) {
        int r = wr * 64 + m * 16 + (lane & 15);
        ah[m] = ld_frag(ldsXh, r, kchunk);
        al[m] = ld_frag(ldsXl, r, kchunk);
      }
#pragma unroll
      for (int n = 0; n < 4; ++n) {
        int r = wc * 64 + n * 16 + (lane & 15);
        bh[n] = ld_frag(ldsYh, r, kchunk);
        bl[n] = ld_frag(ldsYl, r, kchunk);
      }
#pragma unroll
      for (int m = 0; m < 4; ++m)
#pragma unroll
        for (int n = 0; n < 4; ++n) {
          acc[m][n] = __builtin_amdgcn_mfma_f32_16x16x32_bf16(ah[m], bh[n], acc[m][n], 0, 0, 0);
          acc[m][n] = __builtin_amdgcn_mfma_f32_16x16x32_bf16(ah[m], bl[n], acc[m][n], 0, 0, 0);
          acc[m][n] = __builtin_amdgcn_mfma_f32_16x16x32_bf16(al[m], bh[n], acc[m][n], 0, 0, 0);
        }
    }
  }

  // Epilogue: c = dot / max(nx*ny, eps); row-max; atomicMax per global row.
  // C/D layout (16x16x32): col = lane&15, row = (lane>>4)*4 + reg  [m89/m91]
  const int lrow = lane >> 4, lcol = lane & 15;
  float nyv[4];
#pragma unroll
  for (int n = 0; n < 4; ++n) nyv[n] = ny[bj * BN + wc * 64 + n * 16 + lcol];
#pragma unroll
  for (int m = 0; m < 4; ++m) {
#pragma unroll
    for (int q = 0; q < 4; ++q) {
      const int gi = bi * BM + wr * 64 + m * 16 + lrow * 4 + q;
      const float nxv = nx[gi];
      float mx = -4.0f;
#pragma unroll
      for (int n = 0; n < 4; ++n) {
        float c = acc[m][n][q] / fmaxf(nxv * nyv[n], 1e-8f);
        mx = fmaxf(mx, c);
      }
#pragma unroll
      for (int off = 1; off < 16; off <<= 1)
        mx = fmaxf(mx, __shfl_xor(mx, off, 64));
      if (lcol == 0) atomicMax(&rowmax[gi], fkey(mx));
    }
  }
}

// ---------------------------------------------------------------------------
// K3: lp = Normal(1, 0.3).log_prob(max_c); out = sum(exp(lp)*lp)
// ---------------------------------------------------------------------------
__global__ __launch_bounds__(256) void finish_kernel(
    const unsigned* __restrict__ rowmax, float* __restrict__ out)
{
  const int tid = threadIdx.x;
  float s = 0.f;
  for (int i = tid; i < NROW; i += 256) {
    float x = funkey(rowmax[i]);
    float z = (x - 1.0f) * (1.0f / 0.3f);
    // -log(0.3) - 0.5*log(2*pi) = 0.2850342711212634
    float lp = -0.5f * z * z + 0.2850342711212634f;
    float w = expf(lp);
    s += w * lp;
  }
#pragma unroll
  for (int off = 32; off > 0; off >>= 1) s += __shfl_xor(s, off, 64);
  __shared__ float red[4];
  if ((tid & 63) == 0) red[tid >> 6] = s;
  __syncthreads();
  if (tid == 0) out[0] = red[0] + red[1] + red[2] + red[3];
}

// ---------------------------------------------------------------------------
extern "C" void kernel_launch(void* const* d_in, const int* in_sizes, int n_in,
                              void* d_out, int out_size, void* d_ws, size_t ws_size,
                              hipStream_t stream)
{
  const float* ex = (const float*)d_in[0];
  const float* ey = (const float*)d_in[1];
  float* out = (float*)d_out;

  char* ws = (char*)d_ws;
  const size_t mat = (size_t)NROW * DDIM * 2;  // 12.58 MB per bf16 matrix
  __hip_bfloat16* xhi = (__hip_bfloat16*)(ws);
  __hip_bfloat16* xlo = (__hip_bfloat16*)(ws + mat);
  __hip_bfloat16* yhi = (__hip_bfloat16*)(ws + 2 * mat);
  __hip_bfloat16* ylo = (__hip_bfloat16*)(ws + 3 * mat);
  float* nx = (float*)(ws + 4 * mat);
  float* ny = (float*)(ws + 4 * mat + (size_t)NROW * 4);
  unsigned* rowmax = (unsigned*)(ws + 4 * mat + (size_t)2 * NROW * 4);
  // total ws use: ~48.1 MB

  prep_kernel<<<dim3(NROW, 2), 256, 0, stream>>>(ex, ey, xhi, xlo, yhi, ylo,
                                                 nx, ny, rowmax);
  gemm_max_kernel<<<dim3(NTI * NTJ), 256, 0, stream>>>(xhi, xlo, yhi, ylo,
                                                       nx, ny, rowmax);
  finish_kernel<<<1, 256, 0, stream>>>(rowmax, out);
}

// Round 5
// 255.474 us; speedup vs baseline: 1.6816x; 1.6816x over previous
//
#include <hip/hip_runtime.h>
#include <hip/hip_bf16.h>

#define DEVI __device__ __forceinline__

typedef __attribute__((ext_vector_type(8))) short bfrag8;  // 8 bf16 (4 VGPRs)
typedef __attribute__((ext_vector_type(4))) float f32x4;

constexpr int NROW = 8192;
constexpr int DDIM = 768;
constexpr int BM = 128, BN = 128, BK = 64;
constexpr int KSTEPS = DDIM / BK;          // 12
constexpr int TILE_BYTES = BM * BK * 2;    // 16384
constexpr int NTI = NROW / BM;             // 64 row tiles
constexpr int NTJ = NROW / BN;             // 64 col tiles

// ---- exact monotonic float<->uint key for atomicMax on floats ----
DEVI unsigned fkey(float f) {
  unsigned b = __float_as_uint(f);
  return (b & 0x80000000u) ? ~b : (b | 0x80000000u);
}
DEVI float funkey(unsigned k) {
  unsigned b = (k & 0x80000000u) ? (k ^ 0x80000000u) : ~k;
  return __uint_as_float(b);
}

DEVI short f2bf(float f) {
  __hip_bfloat16 h = __float2bfloat16(f);
  union { __hip_bfloat16 h; short s; } u;
  u.h = h;
  return u.s;
}

// ---------------------------------------------------------------------------
// K1: fp32 -> bf16 + row norms + rowmax init.  1 wave per row, vectorized:
// float4 loads (16B/lane), short4 stores (8B/lane).  grid=(2048,2).
// ---------------------------------------------------------------------------
__global__ __launch_bounds__(256) void prep_kernel(
    const float* __restrict__ ex, const float* __restrict__ ey,
    __hip_bfloat16* __restrict__ xh, __hip_bfloat16* __restrict__ yh,
    float* __restrict__ nx, float* __restrict__ ny,
    unsigned* __restrict__ rowmax)
{
  const int which = blockIdx.y;
  const float* __restrict__ src = which ? ey : ex;
  __hip_bfloat16* __restrict__ dst = which ? yh : xh;
  float* __restrict__ nrm = which ? ny : nx;

  const int wave = threadIdx.x >> 6, lane = threadIdx.x & 63;
  const int row = blockIdx.x * 4 + wave;
  const float* __restrict__ srow = src + (size_t)row * DDIM;
  __hip_bfloat16* __restrict__ drow = dst + (size_t)row * DDIM;

  float ss = 0.f;
#pragma unroll
  for (int it = 0; it < 3; ++it) {          // 3 * 256 floats = 768
    const int c = it * 256 + lane * 4;
    float4 v = *reinterpret_cast<const float4*>(srow + c);
    ss += v.x * v.x + v.y * v.y + v.z * v.z + v.w * v.w;
    short4 h;
    h.x = f2bf(v.x); h.y = f2bf(v.y); h.z = f2bf(v.z); h.w = f2bf(v.w);
    *reinterpret_cast<short4*>(drow + c) = h;
  }
#pragma unroll
  for (int off = 32; off > 0; off >>= 1) ss += __shfl_xor(ss, off, 64);
  if (lane == 0) {
    nrm[row] = sqrtf(ss);
    if (!which) rowmax[row] = 0u;  // below every real cosine key
  }
}

// ---------------------------------------------------------------------------
// K2: bf16 GEMM + fused 1/(nx*ny) scale + row-max (atomicMax on uint keys)
// ---------------------------------------------------------------------------

// Stage one 128x64-bf16 tile (row-major, 128B rows) global->LDS.
// LDS dest is linear (global_load_lds constraint); the XOR bank-swizzle
// (chunk ^= row&7 on 16B chunks) is realized by pre-swizzling the per-lane
// GLOBAL source address (guide m173 pattern).
DEVI void stage(const char* __restrict__ src, int row0, int k0, char* ldst,
                int wave, int lane)
{
#pragma unroll
  for (int c = 0; c < 4; ++c) {
    int r = wave * 32 + c * 8 + (lane >> 3);       // row in tile
    int jlog = (lane & 7) ^ (r & 7);               // logical 16B chunk to fetch
    const char* g = src + (size_t)(row0 + r) * (DDIM * 2)
                        + (size_t)(k0 * 2) + jlog * 16;
    char* l = ldst + (wave * 32 + c * 8) * 128;    // wave-uniform base
    __builtin_amdgcn_global_load_lds(
        (const __attribute__((address_space(1))) void*)g,
        (__attribute__((address_space(3))) void*)l, 16, 0, 0);
  }
}

// Read one 16B MFMA fragment from the swizzled tile.
DEVI bfrag8 ld_frag(const char* base, int r, int kchunk) {
  int phys = kchunk ^ (r & 7);
  return *reinterpret_cast<const bfrag8*>(base + r * 128 + phys * 16);
}

__global__ __launch_bounds__(256, 4) void gemm_max_kernel(
    const __hip_bfloat16* __restrict__ xh, const __hip_bfloat16* __restrict__ yh,
    const float* __restrict__ nx, const float* __restrict__ ny,
    unsigned* __restrict__ rowmax)
{
  __shared__ __align__(16) char lds[2 * TILE_BYTES];  // 32 KB -> ~5 blocks/CU
  char* ldsX = lds;
  char* ldsY = lds + TILE_BYTES;

  const int tid = threadIdx.x;
  const int lane = tid & 63;
  const int wave = tid >> 6;
  const int wr = wave >> 1, wc = wave & 1;   // 2x2 waves over 128x128 tile

  // XCD-aware swizzle (4096 % 8 == 0 -> simple form is bijective)
  const int bid = blockIdx.x;
  const int swz = (bid & 7) * ((NTI * NTJ) / 8) + (bid >> 3);
  const int bi = swz >> 6;   // row tile
  const int bj = swz & 63;   // col tile

  f32x4 acc[4][4];
#pragma unroll
  for (int m = 0; m < 4; ++m)
#pragma unroll
    for (int n = 0; n < 4; ++n) acc[m][n] = f32x4{0.f, 0.f, 0.f, 0.f};

  const char* gx = (const char*)xh;
  const char* gy = (const char*)yh;

  for (int ks = 0; ks < KSTEPS; ++ks) {
    const int k0 = ks * BK;
    __syncthreads();  // prior reads of LDS done before overwrite
    stage(gx, bi * BM, k0, ldsX, wave, lane);
    stage(gy, bj * BN, k0, ldsY, wave, lane);
    __syncthreads();  // staging complete (vmcnt drained by barrier)

#pragma unroll
    for (int kk = 0; kk < 2; ++kk) {
      bfrag8 a[4], b[4];
      const int kchunk = kk * 4 + (lane >> 4);
#pragma unroll
      for (int m = 0; m < 4; ++m)
        a[m] = ld_frag(ldsX, wr * 64 + m * 16 + (lane & 15), kchunk);
#pragma unroll
      for (int n = 0; n < 4; ++n)
        b[n] = ld_frag(ldsY, wc * 64 + n * 16 + (lane & 15), kchunk);
#pragma unroll
      for (int m = 0; m < 4; ++m)
#pragma unroll
        for (int n = 0; n < 4; ++n)
          acc[m][n] = __builtin_amdgcn_mfma_f32_16x16x32_bf16(a[m], b[n], acc[m][n], 0, 0, 0);
    }
  }

  // Epilogue: c = dot / max(nx*ny, eps); row-max; atomicMax per global row.
  // C/D layout (16x16x32): col = lane&15, row = (lane>>4)*4 + reg  [m89/m91]
  const int lrow = lane >> 4, lcol = lane & 15;
  float nyv[4];
#pragma unroll
  for (int n = 0; n < 4; ++n) nyv[n] = ny[bj * BN + wc * 64 + n * 16 + lcol];
#pragma unroll
  for (int m = 0; m < 4; ++m) {
#pragma unroll
    for (int q = 0; q < 4; ++q) {
      const int gi = bi * BM + wr * 64 + m * 16 + lrow * 4 + q;
      const float nxv = nx[gi];
      float mx = -4.0f;
#pragma unroll
      for (int n = 0; n < 4; ++n) {
        float c = acc[m][n][q] / fmaxf(nxv * nyv[n], 1e-8f);
        mx = fmaxf(mx, c);
      }
#pragma unroll
      for (int off = 1; off < 16; off <<= 1)
        mx = fmaxf(mx, __shfl_xor(mx, off, 64));
      if (lcol == 0) atomicMax(&rowmax[gi], fkey(mx));
    }
  }
}

// ---------------------------------------------------------------------------
// K3: lp = Normal(1, 0.3).log_prob(max_c); out = sum(exp(lp)*lp)
// ---------------------------------------------------------------------------
__global__ __launch_bounds__(256) void finish_kernel(
    const unsigned* __restrict__ rowmax, float* __restrict__ out)
{
  const int tid = threadIdx.x;
  float s = 0.f;
  for (int i = tid; i < NROW; i += 256) {
    float x = funkey(rowmax[i]);
    float z = (x - 1.0f) * (1.0f / 0.3f);
    // -log(0.3) - 0.5*log(2*pi) = 0.2850342711212634
    float lp = -0.5f * z * z + 0.2850342711212634f;
    float w = expf(lp);
    s += w * lp;
  }
#pragma unroll
  for (int off = 32; off > 0; off >>= 1) s += __shfl_xor(s, off, 64);
  __shared__ float red[4];
  if ((tid & 63) == 0) red[tid >> 6] = s;
  __syncthreads();
  if (tid == 0) out[0] = red[0] + red[1] + red[2] + red[3];
}

// ---------------------------------------------------------------------------
extern "C" void kernel_launch(void* const* d_in, const int* in_sizes, int n_in,
                              void* d_out, int out_size, void* d_ws, size_t ws_size,
                              hipStream_t stream)
{
  const float* ex = (const float*)d_in[0];
  const float* ey = (const float*)d_in[1];
  float* out = (float*)d_out;

  char* ws = (char*)d_ws;
  const size_t mat = (size_t)NROW * DDIM * 2;  // 12.58 MB per bf16 matrix
  __hip_bfloat16* xh = (__hip_bfloat16*)(ws);
  __hip_bfloat16* yh = (__hip_bfloat16*)(ws + mat);
  float* nx = (float*)(ws + 2 * mat);
  float* ny = (float*)(ws + 2 * mat + (size_t)NROW * 4);
  unsigned* rowmax = (unsigned*)(ws + 2 * mat + (size_t)2 * NROW * 4);
  // total ws use: ~25.3 MB

  prep_kernel<<<dim3(NROW / 4, 2), 256, 0, stream>>>(ex, ey, xh, yh,
                                                     nx, ny, rowmax);
  gemm_max_kernel<<<dim3(NTI * NTJ), 256, 0, stream>>>(xh, yh, nx, ny, rowmax);
  finish_kernel<<<1, 256, 0, stream>>>(rowmax, out);
}